// Round 3
// baseline (146.614 us; speedup 1.0000x reference)
//
#include <hip/hip_runtime.h>

// ---------------------------------------------------------------------------
// SampledSoftmaxLoss: loss = mean_n( lse_n - pos_logit_n )
// N=4096 queries, D=512, 8192 candidate cols (4096 inbatch + 4096 uniform).
// Round 3: 256x256 tile / 8 waves / 2-phase double-buffered LDS pipeline,
// one output tile per block (no flash rescale), fused prep+pos_logit.
// ---------------------------------------------------------------------------

#define N_ROWS 4096
#define DIM    512
#define N_INB  4096
#define N_CAND 8192
#define BM 256
#define BN 256
#define BK 64
#define NCT 32                // candidate column tiles
#define NEG_LOG_Q_UNIFORM 12.2060727f   // -log(1/200000)

typedef __bf16 bf16x8 __attribute__((ext_vector_type(8)));
typedef float  f32x4  __attribute__((ext_vector_type(4)));

#define GLDS16(gp, lp) __builtin_amdgcn_global_load_lds( \
    (const __attribute__((address_space(1))) void*)(gp), \
    (__attribute__((address_space(3))) void*)(lp), 16, 0, 0)

__device__ __forceinline__ unsigned short f2bf(float f) {
  union { float f; unsigned u; } v; v.f = f;
  unsigned u = v.u;
  unsigned r = (u + 0x7FFFu + ((u >> 16) & 1u)) >> 16;   // round-nearest-even
  return (unsigned short)r;
}

__device__ __forceinline__ float inv_tau_of(const float* log_tau) {
  float tau = expf(log_tau[0]);
  tau = fminf(fmaxf(tau, 0.01f), 100.0f);
  return 1.0f / tau;
}

// --- fused prep: one wave per candidate row j (0..8191).
//     Cb[j]   = bf16(item_emb[src(j)])
//     Qb[j]   = bf16(hidden[j] * inv_tau)             (j < 4096)
//     pos_l[j]= fp32 dot(hidden[j], item_emb[pos[j]]) * inv_tau  (j < 4096)
//     bias[j] = -log_q[pos[j]]  or  +12.206
__global__ void prep_kernel(const float* __restrict__ hidden,
                            const int* __restrict__ positives,
                            const int* __restrict__ uniform_ids,
                            const float* __restrict__ item_emb,
                            const float* __restrict__ log_tau,
                            const float* __restrict__ log_q,
                            unsigned short* __restrict__ Qb,
                            unsigned short* __restrict__ Cb,
                            float* __restrict__ bias,
                            float* __restrict__ pos_logit) {
  const int j = (blockIdx.x * blockDim.x + threadIdx.x) >> 6;
  const int lane = threadIdx.x & 63;
  if (j >= N_CAND) return;
  const float inv_tau = inv_tau_of(log_tau);
  const int src = (j < N_INB) ? positives[j] : uniform_ids[j - N_INB];
  const float4* erow = reinterpret_cast<const float4*>(item_emb + (size_t)src * DIM);
  const float4 e0 = erow[lane], e1 = erow[lane + 64];
  ushort4 c0, c1;
  c0.x = f2bf(e0.x); c0.y = f2bf(e0.y); c0.z = f2bf(e0.z); c0.w = f2bf(e0.w);
  c1.x = f2bf(e1.x); c1.y = f2bf(e1.y); c1.z = f2bf(e1.z); c1.w = f2bf(e1.w);
  reinterpret_cast<ushort4*>(Cb)[(size_t)j * 128 + lane]      = c0;
  reinterpret_cast<ushort4*>(Cb)[(size_t)j * 128 + lane + 64] = c1;
  if (j < N_INB) {
    const float4* qrow = reinterpret_cast<const float4*>(hidden + (size_t)j * DIM);
    const float4 q0 = qrow[lane], q1 = qrow[lane + 64];
    ushort4 o0, o1;
    o0.x = f2bf(q0.x * inv_tau); o0.y = f2bf(q0.y * inv_tau);
    o0.z = f2bf(q0.z * inv_tau); o0.w = f2bf(q0.w * inv_tau);
    o1.x = f2bf(q1.x * inv_tau); o1.y = f2bf(q1.y * inv_tau);
    o1.z = f2bf(q1.z * inv_tau); o1.w = f2bf(q1.w * inv_tau);
    reinterpret_cast<ushort4*>(Qb)[(size_t)j * 128 + lane]      = o0;
    reinterpret_cast<ushort4*>(Qb)[(size_t)j * 128 + lane + 64] = o1;
    float d = q0.x * e0.x + q0.y * e0.y + q0.z * e0.z + q0.w * e0.w
            + q1.x * e1.x + q1.y * e1.y + q1.z * e1.z + q1.w * e1.w;
#pragma unroll
    for (int off = 32; off > 0; off >>= 1) d += __shfl_xor(d, off);
    if (lane == 0) {
      pos_logit[j] = d * inv_tau;
      bias[j] = -log_q[src];
    }
  } else if (lane == 0) {
    bias[j] = NEG_LOG_Q_UNIFORM;
  }
}

// --- main: one 256x256 logit tile per block. 8 waves (2M x 4N), per-wave
//     128x64 output, BK=64, double-buffered LDS, 1 barrier per K-step.
__launch_bounds__(512, 2)
__global__ void main_kernel(const unsigned short* __restrict__ Qb,
                            const unsigned short* __restrict__ Cb,
                            const float* __restrict__ bias,
                            float* __restrict__ part_m,
                            float* __restrict__ part_l) {
  __shared__ unsigned short lds_a[2][BM * BK];   // 2 x 32 KB
  __shared__ unsigned short lds_b[2][BN * BK];   // 2 x 32 KB
  __shared__ float pl_lds[4][BM];
  __shared__ float pm_w[8];

  const int tid = threadIdx.x;
  const int w = tid >> 6, lane = tid & 63;
  const int wr = w >> 2, wc = w & 3;
  const int l15 = lane & 15, l4 = lane >> 4;
  const int rb = blockIdx.x;                     // 0..15 row block
  const int ct = blockIdx.y;                     // 0..31 col tile
  const int row0 = rb * BM;
  const int cand0 = ct * BN;

  if (ct == rb) {                                // fully-masked inbatch tile
    if (tid < BM) {
      part_m[(size_t)ct * N_ROWS + row0 + tid] = -INFINITY;
      part_l[(size_t)ct * N_ROWS + row0 + tid] = 0.0f;
    }
    return;
  }

  // per-lane bias for its 4 columns (hot in L2)
  float bias_f[4];
#pragma unroll
  for (int fn = 0; fn < 4; ++fn)
    bias_f[fn] = bias[cand0 + wc * 64 + fn * 16 + l15];

  f32x4 acc[8][4];
#pragma unroll
  for (int fm = 0; fm < 8; ++fm)
#pragma unroll
    for (int fn = 0; fn < 4; ++fn)
#pragma unroll
      for (int i = 0; i < 4; ++i) acc[fm][fn][i] = 0.0f;

  // Stage one K-tile (A 256x64 + B 256x64) into buf. 16B/lane granules,
  // XOR granule swizzle (rule #21): linear LDS dest, source pre-swizzled,
  // read applies the same involution.
#define STAGE(buf, k0)                                                        \
  {                                                                           \
    _Pragma("unroll")                                                         \
    for (int it = 0; it < 4; ++it) {                                          \
      const int s = it * 512 + tid;                                           \
      const int r = s >> 3, kc = s & 7;                                       \
      GLDS16(Qb + (size_t)(row0 + r) * DIM + (k0) + ((kc ^ (r & 7)) << 3),    \
             (char*)&lds_a[buf][0] + it * 8192 + w * 1024);                   \
    }                                                                         \
    _Pragma("unroll")                                                         \
    for (int it = 0; it < 4; ++it) {                                          \
      const int s = it * 512 + tid;                                           \
      const int r = s >> 3, kc = s & 7;                                       \
      GLDS16(Cb + (size_t)(cand0 + r) * DIM + (k0) + ((kc ^ (r & 7)) << 3),   \
             (char*)&lds_b[buf][0] + it * 8192 + w * 1024);                   \
    }                                                                         \
  }

  STAGE(0, 0);
  __syncthreads();                               // buf0 ready (vmcnt drained)

  int cur = 0;
  for (int k = 0; k < DIM / BK; ++k) {
    if (k + 1 < DIM / BK) STAGE(cur ^ 1, (k + 1) * BK);   // prefetch overlaps

#pragma unroll
    for (int ks = 0; ks < BK; ks += 32) {
      const int kc = (ks >> 3) + l4;             // k-granule 0..7
      bf16x8 a[8], b[4];
#pragma unroll
      for (int fm = 0; fm < 8; ++fm) {
        const int rr = wr * 128 + fm * 16 + l15;
        a[fm] = *reinterpret_cast<const bf16x8*>(
            &lds_a[cur][rr * 64 + ((kc ^ (rr & 7)) << 3)]);
      }
#pragma unroll
      for (int fn = 0; fn < 4; ++fn) {
        const int rr = wc * 64 + fn * 16 + l15;
        b[fn] = *reinterpret_cast<const bf16x8*>(
            &lds_b[cur][rr * 64 + ((kc ^ (rr & 7)) << 3)]);
      }
#pragma unroll
      for (int fm = 0; fm < 8; ++fm)
#pragma unroll
        for (int fn = 0; fn < 4; ++fn)
          acc[fm][fn] = __builtin_amdgcn_mfma_f32_16x16x32_bf16(
              a[fm], b[fn], acc[fm][fn], 0, 0, 0);
    }
    __syncthreads();          // drains vmcnt (next buf ready) + lgkm (reads done)
    cur ^= 1;
  }

  // ---- epilogue: bias, block max, exp row-sums, (m,l) partial ----
  float mt = -INFINITY;
#pragma unroll
  for (int fm = 0; fm < 8; ++fm)
#pragma unroll
    for (int fn = 0; fn < 4; ++fn)
#pragma unroll
      for (int i = 0; i < 4; ++i) {
        const float v = acc[fm][fn][i] + bias_f[fn];
        acc[fm][fn][i] = v;
        mt = fmaxf(mt, v);
      }
#pragma unroll
  for (int off = 1; off < 64; off <<= 1) mt = fmaxf(mt, __shfl_xor(mt, off));
  if (lane == 0) pm_w[w] = mt;
  __syncthreads();
  float M = pm_w[0];
#pragma unroll
  for (int ww = 1; ww < 8; ++ww) M = fmaxf(M, pm_w[ww]);

#pragma unroll
  for (int fm = 0; fm < 8; ++fm)
#pragma unroll
    for (int i = 0; i < 4; ++i) {
      float s = 0.0f;
#pragma unroll
      for (int fn = 0; fn < 4; ++fn) s += __expf(acc[fm][fn][i] - M);
      s += __shfl_xor(s, 1); s += __shfl_xor(s, 2);
      s += __shfl_xor(s, 4); s += __shfl_xor(s, 8);
      if (l15 == 0) pl_lds[wc][wr * 128 + fm * 16 + l4 * 4 + i] = s;
    }
  __syncthreads();
  if (tid < BM) {
    const float l = pl_lds[0][tid] + pl_lds[1][tid] +
                    pl_lds[2][tid] + pl_lds[3][tid];
    part_m[(size_t)ct * N_ROWS + row0 + tid] = M;
    part_l[(size_t)ct * N_ROWS + row0 + tid] = l;
  }
}

// --- finalize: combine 32 col-tile partials + pos_logit, mean over rows
__global__ void finalize_kernel(const float* __restrict__ part_m,
                                const float* __restrict__ part_l,
                                const float* __restrict__ pos_logit,
                                float* __restrict__ out) {
  __shared__ float red[256];
  float local = 0.0f;
  for (int row = threadIdx.x; row < N_ROWS; row += 256) {
    const float pl = pos_logit[row];
    float M = pl;
    for (int s = 0; s < NCT; ++s) M = fmaxf(M, part_m[(size_t)s * N_ROWS + row]);
    float L = expf(pl - M);
    for (int s = 0; s < NCT; ++s) {
      const float l = part_l[(size_t)s * N_ROWS + row];
      if (l > 0.0f) L += l * expf(part_m[(size_t)s * N_ROWS + row] - M);
    }
    local += M + logf(L) - pl;
  }
  red[threadIdx.x] = local;
  __syncthreads();
  for (int s = 128; s > 0; s >>= 1) {
    if (threadIdx.x < s) red[threadIdx.x] += red[threadIdx.x + s];
    __syncthreads();
  }
  if (threadIdx.x == 0) out[0] = red[0] * (1.0f / N_ROWS);
}

extern "C" void kernel_launch(void* const* d_in, const int* in_sizes, int n_in,
                              void* d_out, int out_size, void* d_ws, size_t ws_size,
                              hipStream_t stream) {
  const float* hidden      = (const float*)d_in[0];
  // d_in[1] = mask (all true by construction; unused)
  const int*   positives   = (const int*)d_in[2];
  const int*   uniform_ids = (const int*)d_in[3];
  const float* item_emb    = (const float*)d_in[4];
  const float* log_tau     = (const float*)d_in[5];
  const float* log_q       = (const float*)d_in[6];
  float* out = (float*)d_out;

  char* ws = (char*)d_ws;
  unsigned short* Qb = (unsigned short*)ws;  ws += (size_t)N_ROWS * DIM * 2;  // 4 MB
  unsigned short* Cb = (unsigned short*)ws;  ws += (size_t)N_CAND * DIM * 2;  // 8 MB
  float* bias   = (float*)ws;                ws += (size_t)N_CAND * 4;
  float* pos_l  = (float*)ws;                ws += (size_t)N_ROWS * 4;
  float* pm     = (float*)ws;                ws += (size_t)NCT * N_ROWS * 4;
  float* pl     = (float*)ws;                ws += (size_t)NCT * N_ROWS * 4;

  prep_kernel<<<(N_CAND * 64) / 256, 256, 0, stream>>>(
      hidden, positives, uniform_ids, item_emb, log_tau, log_q,
      Qb, Cb, bias, pos_l);
  main_kernel<<<dim3(N_ROWS / BM, NCT), 512, 0, stream>>>(Qb, Cb, bias, pm, pl);
  finalize_kernel<<<1, 256, 0, stream>>>(pm, pl, pos_l, out);
}

// Round 4
// 74.493 us; speedup vs baseline: 1.9682x; 1.9682x over previous
//
#include <hip/hip_runtime.h>

// ---------------------------------------------------------------------------
// SampledSoftmaxLoss: loss = mean_n( lse_n - pos_logit_n )
// N=4096 queries, D=512, 8192 candidate cols (4096 inbatch + 4096 uniform).
// Round 4: 256x256 tile, 8 waves, K-loop unrolled x2 with STATIC double
// buffers (A0/B0/A1/B1) so the compiler proves prefetch/ds_read disjointness
// and the only vmcnt(0) drain sits at the barrier (prefetch overlaps MFMA).
// ---------------------------------------------------------------------------

#define N_ROWS 4096
#define DIM    512
#define N_INB  4096
#define N_CAND 8192
#define BM 256
#define BN 256
#define BK 64
#define NKT (DIM / BK)        // 8 K-tiles
#define NCT 32                // candidate column tiles
#define NEG_LOG_Q_UNIFORM 12.2060727f   // -log(1/200000)

typedef __bf16 bf16x8 __attribute__((ext_vector_type(8)));
typedef float  f32x4  __attribute__((ext_vector_type(4)));

#define GLDS16(gp, lp) __builtin_amdgcn_global_load_lds( \
    (const __attribute__((address_space(1))) void*)(gp), \
    (__attribute__((address_space(3))) void*)(lp), 16, 0, 0)

__device__ __forceinline__ unsigned short f2bf(float f) {
  union { float f; unsigned u; } v; v.f = f;
  unsigned u = v.u;
  unsigned r = (u + 0x7FFFu + ((u >> 16) & 1u)) >> 16;   // round-nearest-even
  return (unsigned short)r;
}

__device__ __forceinline__ float inv_tau_of(const float* log_tau) {
  float tau = expf(log_tau[0]);
  tau = fminf(fmaxf(tau, 0.01f), 100.0f);
  return 1.0f / tau;
}

// --- fused prep: one wave per candidate row j (0..8191).
__global__ void prep_kernel(const float* __restrict__ hidden,
                            const int* __restrict__ positives,
                            const int* __restrict__ uniform_ids,
                            const float* __restrict__ item_emb,
                            const float* __restrict__ log_tau,
                            const float* __restrict__ log_q,
                            unsigned short* __restrict__ Qb,
                            unsigned short* __restrict__ Cb,
                            float* __restrict__ bias,
                            float* __restrict__ pos_logit) {
  const int j = (blockIdx.x * blockDim.x + threadIdx.x) >> 6;
  const int lane = threadIdx.x & 63;
  if (j >= N_CAND) return;
  const float inv_tau = inv_tau_of(log_tau);
  const int src = (j < N_INB) ? positives[j] : uniform_ids[j - N_INB];
  const float4* erow = reinterpret_cast<const float4*>(item_emb + (size_t)src * DIM);
  const float4 e0 = erow[lane], e1 = erow[lane + 64];
  ushort4 c0, c1;
  c0.x = f2bf(e0.x); c0.y = f2bf(e0.y); c0.z = f2bf(e0.z); c0.w = f2bf(e0.w);
  c1.x = f2bf(e1.x); c1.y = f2bf(e1.y); c1.z = f2bf(e1.z); c1.w = f2bf(e1.w);
  reinterpret_cast<ushort4*>(Cb)[(size_t)j * 128 + lane]      = c0;
  reinterpret_cast<ushort4*>(Cb)[(size_t)j * 128 + lane + 64] = c1;
  if (j < N_INB) {
    const float4* qrow = reinterpret_cast<const float4*>(hidden + (size_t)j * DIM);
    const float4 q0 = qrow[lane], q1 = qrow[lane + 64];
    ushort4 o0, o1;
    o0.x = f2bf(q0.x * inv_tau); o0.y = f2bf(q0.y * inv_tau);
    o0.z = f2bf(q0.z * inv_tau); o0.w = f2bf(q0.w * inv_tau);
    o1.x = f2bf(q1.x * inv_tau); o1.y = f2bf(q1.y * inv_tau);
    o1.z = f2bf(q1.z * inv_tau); o1.w = f2bf(q1.w * inv_tau);
    reinterpret_cast<ushort4*>(Qb)[(size_t)j * 128 + lane]      = o0;
    reinterpret_cast<ushort4*>(Qb)[(size_t)j * 128 + lane + 64] = o1;
    float d = q0.x * e0.x + q0.y * e0.y + q0.z * e0.z + q0.w * e0.w
            + q1.x * e1.x + q1.y * e1.y + q1.z * e1.z + q1.w * e1.w;
#pragma unroll
    for (int off = 32; off > 0; off >>= 1) d += __shfl_xor(d, off);
    if (lane == 0) {
      pos_logit[j] = d * inv_tau;
      bias[j] = -log_q[src];
    }
  } else if (lane == 0) {
    bias[j] = NEG_LOG_Q_UNIFORM;
  }
}

// --- main: one 256x256 logit tile per block, 8 waves (2M x 4N), per-wave
//     128x64 output. Static double-buffered LDS, prefetch-overlap pipeline.
__launch_bounds__(512, 2)
__global__ void main_kernel(const unsigned short* __restrict__ Qb,
                            const unsigned short* __restrict__ Cb,
                            const float* __restrict__ bias,
                            float* __restrict__ part_m,
                            float* __restrict__ part_l) {
  __shared__ unsigned short A0[BM * BK], B0[BN * BK];   // 32 KB each
  __shared__ unsigned short A1[BM * BK], B1[BN * BK];
  __shared__ float pl_lds[4][BM];
  __shared__ float pm_w[8];

  const int tid = threadIdx.x;
  const int w = tid >> 6, lane = tid & 63;
  const int wr = w >> 2, wc = w & 3;
  const int l15 = lane & 15, l4 = lane >> 4;
  const int rb = blockIdx.x;                     // 0..15 row block
  const int ct = blockIdx.y;                     // 0..31 col tile
  const int row0 = rb * BM;
  const int cand0 = ct * BN;

  if (ct == rb) {                                // fully-masked inbatch tile
    if (tid < BM) {
      part_m[(size_t)ct * N_ROWS + row0 + tid] = -INFINITY;
      part_l[(size_t)ct * N_ROWS + row0 + tid] = 0.0f;
    }
    return;
  }

  float bias_f[4];
#pragma unroll
  for (int fn = 0; fn < 4; ++fn)
    bias_f[fn] = bias[cand0 + wc * 64 + fn * 16 + l15];

  f32x4 acc[8][4];
#pragma unroll
  for (int fm = 0; fm < 8; ++fm)
#pragma unroll
    for (int fn = 0; fn < 4; ++fn)
#pragma unroll
      for (int i = 0; i < 4; ++i) acc[fm][fn][i] = 0.0f;

  // Stage one K-tile (A 256x64 + B 256x64). 16B granules, XOR granule
  // swizzle (rule #21): linear LDS dest, source pre-swizzled, read applies
  // the same involution. LA/LB are statically distinct arrays.
#define STAGE(LA, LB, k0)                                                     \
  {                                                                           \
    _Pragma("unroll")                                                         \
    for (int it = 0; it < 4; ++it) {                                          \
      const int s = it * 512 + tid;                                           \
      const int r = s >> 3, kc = s & 7;                                       \
      GLDS16(Qb + (size_t)(row0 + r) * DIM + (k0) + ((kc ^ (r & 7)) << 3),    \
             (char*)(LA) + it * 8192 + w * 1024);                             \
    }                                                                         \
    _Pragma("unroll")                                                         \
    for (int it = 0; it < 4; ++it) {                                          \
      const int s = it * 512 + tid;                                           \
      const int r = s >> 3, kc = s & 7;                                       \
      GLDS16(Cb + (size_t)(cand0 + r) * DIM + (k0) + ((kc ^ (r & 7)) << 3),   \
             (char*)(LB) + it * 8192 + w * 1024);                             \
    }                                                                         \
  }

  // 2 ks-steps of 12 ds_read_b128 + 32 MFMA each, from static arrays.
#define COMPUTE(LA, LB)                                                       \
  {                                                                           \
    _Pragma("unroll")                                                         \
    for (int ks = 0; ks < BK; ks += 32) {                                     \
      const int kc = (ks >> 3) + l4;                                          \
      bf16x8 a[8], b[4];                                                      \
      _Pragma("unroll")                                                       \
      for (int fm = 0; fm < 8; ++fm) {                                        \
        const int rr = wr * 128 + fm * 16 + l15;                              \
        a[fm] = *reinterpret_cast<const bf16x8*>(                             \
            &(LA)[rr * 64 + ((kc ^ (rr & 7)) << 3)]);                         \
      }                                                                       \
      _Pragma("unroll")                                                       \
      for (int fn = 0; fn < 4; ++fn) {                                        \
        const int rr = wc * 64 + fn * 16 + l15;                               \
        b[fn] = *reinterpret_cast<const bf16x8*>(                             \
            &(LB)[rr * 64 + ((kc ^ (rr & 7)) << 3)]);                         \
      }                                                                       \
      _Pragma("unroll")                                                       \
      for (int fm = 0; fm < 8; ++fm)                                          \
        _Pragma("unroll")                                                     \
        for (int fn = 0; fn < 4; ++fn)                                        \
          acc[fm][fn] = __builtin_amdgcn_mfma_f32_16x16x32_bf16(              \
              a[fm], b[fn], acc[fm][fn], 0, 0, 0);                            \
    }                                                                         \
  }

  STAGE(A0, B0, 0);
  __syncthreads();                               // drain: buf0 ready

  for (int k2 = 0; k2 < NKT; k2 += 2) {
    // half A: compute tile k2 from buf0; prefetch tile k2+1 into buf1.
    STAGE(A1, B1, (k2 + 1) * BK);                // k2+1 <= 7 always
    COMPUTE(A0, B0);
    __syncthreads();                             // buf1 ready; buf0 reads done
    // half B: compute tile k2+1 from buf1; prefetch tile k2+2 into buf0.
    if (k2 + 2 < NKT) STAGE(A0, B0, (k2 + 2) * BK);
    COMPUTE(A1, B1);
    __syncthreads();                             // buf0 ready; buf1 reads done
  }

  // ---- epilogue: bias, block max, exp row-sums, (m,l) partial ----
  float mt = -INFINITY;
#pragma unroll
  for (int fm = 0; fm < 8; ++fm)
#pragma unroll
    for (int fn = 0; fn < 4; ++fn)
#pragma unroll
      for (int i = 0; i < 4; ++i) {
        const float v = acc[fm][fn][i] + bias_f[fn];
        acc[fm][fn][i] = v;
        mt = fmaxf(mt, v);
      }
#pragma unroll
  for (int off = 1; off < 64; off <<= 1) mt = fmaxf(mt, __shfl_xor(mt, off));
  if (lane == 0) pm_w[w] = mt;
  __syncthreads();
  float M = pm_w[0];
#pragma unroll
  for (int ww = 1; ww < 8; ++ww) M = fmaxf(M, pm_w[ww]);

#pragma unroll
  for (int fm = 0; fm < 8; ++fm)
#pragma unroll
    for (int i = 0; i < 4; ++i) {
      float s = 0.0f;
#pragma unroll
      for (int fn = 0; fn < 4; ++fn) s += __expf(acc[fm][fn][i] - M);
      s += __shfl_xor(s, 1); s += __shfl_xor(s, 2);
      s += __shfl_xor(s, 4); s += __shfl_xor(s, 8);
      if (l15 == 0) pl_lds[wc][wr * 128 + fm * 16 + l4 * 4 + i] = s;
    }
  __syncthreads();
  if (tid < BM) {
    const float l = pl_lds[0][tid] + pl_lds[1][tid] +
                    pl_lds[2][tid] + pl_lds[3][tid];
    part_m[(size_t)ct * N_ROWS + row0 + tid] = M;
    part_l[(size_t)ct * N_ROWS + row0 + tid] = l;
  }
}

// --- finalize: 16 blocks x 256 threads, one row per thread, atomic combine.
__global__ void finalize_kernel(const float* __restrict__ part_m,
                                const float* __restrict__ part_l,
                                const float* __restrict__ pos_logit,
                                float* __restrict__ out) {
  __shared__ float red[256];
  const int row = blockIdx.x * 256 + threadIdx.x;
  const float pl = pos_logit[row];
  float M = pl;
#pragma unroll
  for (int s = 0; s < NCT; ++s) M = fmaxf(M, part_m[(size_t)s * N_ROWS + row]);
  float L = expf(pl - M);
#pragma unroll
  for (int s = 0; s < NCT; ++s) {
    const float l = part_l[(size_t)s * N_ROWS + row];
    if (l > 0.0f) L += l * expf(part_m[(size_t)s * N_ROWS + row] - M);
  }
  red[threadIdx.x] = M + logf(L) - pl;
  __syncthreads();
  for (int s = 128; s > 0; s >>= 1) {
    if (threadIdx.x < s) red[threadIdx.x] += red[threadIdx.x + s];
    __syncthreads();
  }
  if (threadIdx.x == 0) atomicAdd(out, red[0] * (1.0f / N_ROWS));
}

extern "C" void kernel_launch(void* const* d_in, const int* in_sizes, int n_in,
                              void* d_out, int out_size, void* d_ws, size_t ws_size,
                              hipStream_t stream) {
  const float* hidden      = (const float*)d_in[0];
  // d_in[1] = mask (all true by construction; unused)
  const int*   positives   = (const int*)d_in[2];
  const int*   uniform_ids = (const int*)d_in[3];
  const float* item_emb    = (const float*)d_in[4];
  const float* log_tau     = (const float*)d_in[5];
  const float* log_q       = (const float*)d_in[6];
  float* out = (float*)d_out;

  char* ws = (char*)d_ws;
  unsigned short* Qb = (unsigned short*)ws;  ws += (size_t)N_ROWS * DIM * 2;  // 4 MB
  unsigned short* Cb = (unsigned short*)ws;  ws += (size_t)N_CAND * DIM * 2;  // 8 MB
  float* bias   = (float*)ws;                ws += (size_t)N_CAND * 4;
  float* pos_l  = (float*)ws;                ws += (size_t)N_ROWS * 4;
  float* pm     = (float*)ws;                ws += (size_t)NCT * N_ROWS * 4;
  float* pl     = (float*)ws;                ws += (size_t)NCT * N_ROWS * 4;

  hipMemsetAsync(out, 0, sizeof(float), stream);
  prep_kernel<<<(N_CAND * 64) / 256, 256, 0, stream>>>(
      hidden, positives, uniform_ids, item_emb, log_tau, log_q,
      Qb, Cb, bias, pos_l);
  main_kernel<<<dim3(N_ROWS / BM, NCT), 512, 0, stream>>>(Qb, Cb, bias, pm, pl);
  finalize_kernel<<<N_ROWS / 256, 256, 0, stream>>>(pm, pl, pos_l, out);
}